// Round 9
// baseline (2003.003 us; speedup 1.0000x reference)
//
#include <hip/hip_runtime.h>
#include <hip/hip_bf16.h>

#define DD 1024
#define MDD 256
#define LL 2048
#define BB 4
#define NROWS (BB*LL)   // 8192
#define NCH 8
#define TCH (LL/NCH)    // 256 steps per chunk

typedef short bf16x8 __attribute__((ext_vector_type(8)));
typedef float f32x4 __attribute__((ext_vector_type(4)));
typedef int   i32x4 __attribute__((ext_vector_type(4)));

__device__ __forceinline__ short f2b(float x){
  __hip_bfloat16 h = __float2bfloat16(x);
  return *reinterpret_cast<short*>(&h);
}
__device__ __forceinline__ float b2f(short s){
  return __uint_as_float(((unsigned)(unsigned short)s) << 16);
}
__device__ __forceinline__ float frcp(float x){
#if __has_builtin(__builtin_amdgcn_rcpf)
  return __builtin_amdgcn_rcpf(x);
#else
  float r; asm("v_rcp_f32 %0, %1" : "=v"(r) : "v"(x)); return r;
#endif
}
__device__ __forceinline__ float fsigmoid(float x){
  return frcp(1.f + __expf(-x));
}
__device__ __forceinline__ float sel4(f32x4 a, int kg){
  float lo = (kg & 1) ? a[1] : a[0];
  float hi = (kg & 1) ? a[3] : a[2];
  return (kg & 2) ? hi : lo;
}

// ---------------- fused weight conversion / bias prep ----------------
struct CvtDesc {
  const float* src; const float* src2; short* dstb; float* dstf;
  int n, cols, sld, soff, dld, mode;
};
struct CvtArgs { CvtDesc d[20]; };

__global__ __launch_bounds__(256) void cvt_all(CvtArgs a){
  int di = blockIdx.x >> 6;
  CvtDesc d = a.d[di];
  int base = (blockIdx.x & 63)*256 + threadIdx.x;
  for (int i = base; i < d.n; i += 64*256){
    int r = i / d.cols, c = i - r*d.cols;
    float v = d.src[(size_t)r*d.sld + d.soff + c];
    if (d.mode == 2) v += d.src2[i];
    if (d.mode == 0) d.dstb[(size_t)r*d.dld + c] = f2b(v);
    else             d.dstf[i] = v;
  }
}

// ---------------- rmsnorm (f32 in -> bf16 out, strided out) ----------------
__global__ __launch_bounds__(256) void rmsnorm_k(const float* __restrict__ x,
                                                 const float* __restrict__ w,
                                                 short* __restrict__ xn){
  int row = blockIdx.x, tid = threadIdx.x;
  const float* xr = x + (size_t)row*DD;
  float4 v = *(const float4*)&xr[tid*4];
  float ss = v.x*v.x + v.y*v.y + v.z*v.z + v.w*v.w;
  __shared__ float red[256];
  red[tid] = ss; __syncthreads();
  for (int s = 128; s > 0; s >>= 1){ if (tid < s) red[tid] += red[tid+s]; __syncthreads(); }
  float scale = rsqrtf(red[0]/(float)DD + 1e-6f);
  const float* wr = w + tid*4;
  short4 o;
  o.x = f2b(v.x*wr[0]*scale); o.y = f2b(v.y*wr[1]*scale);
  o.z = f2b(v.z*wr[2]*scale); o.w = f2b(v.w*wr[3]*scale);
  *(short4*)&xn[(size_t)row*2048 + tid*4] = o;
}

// ---------------- depthwise causal conv K=5 ----------------
__global__ __launch_bounds__(256) void dwconv_k(const short* __restrict__ xnA,
                                                const float* __restrict__ dwk,
                                                const float* __restrict__ dwb,
                                                short* __restrict__ xcA){
  size_t i = (size_t)blockIdx.x*256 + threadIdx.x;
  int d = (int)(i & (DD-1));
  int l = (int)((i >> 10) & (LL-1));
  int b = (int)(i >> 21);
  float acc = dwb[d];
  const float* kk = dwk + d*5;
  #pragma unroll
  for (int k = 0; k < 5; ++k){
    int ll = l + k - 4;
    if (ll >= 0) acc += b2f(xnA[((size_t)(b*LL + ll))*2048 + d]) * kk[k];
  }
  xcA[((size_t)(b*LL + l))*2048 + 1024 + d] = f2b(acc);
}

// ---------------- pipelined fused dispatch ----------------
// Job types: 0 = 128x128 GEMM (8 waves, wave = 64x32 subtile), 1 = combine (router+mix+rmsnorm).
// remap 0: bm = bm0 + lb2 (contiguous). remap 1: chunk-interleave (rows b*L+t, chunk cstart+):
//   c = cstart + (lb2>>3), q = lb2&7, bm = (q>>1)*16 + c*2 + (q&1).
// outmode: 0 f32 store, 2 bf16 store, 3 f32 accumulate + bf16 copy. act: 0/1 silu/2 gelu.
// permute: orow = (gr&3)*LL + (gr>>2) (m2all row-space t*4+b -> b*L+t).
struct Job {
  const short* A; const short* Bw; const float* bias;
  const float* add0; const float* add1; void* Cf; short* C2;
  int N, K, lda, ldb, bn, nblocks, bm0, cstart, act, outmode, permute, remap, type;
};
struct PipeArgs { Job j[8]; int njobs; };

__global__ __launch_bounds__(512, 2) void pipe_k(
    const float* __restrict__ fxu, const short* __restrict__ Wfu,
    const float* __restrict__ m0, float* __restrict__ mstate,
    short* __restrict__ m2all, float* __restrict__ newmem,
    int t0, int nsteps, int has_scan, PipeArgs pa){
  __shared__ __align__(16) short lds[8192];   // 16 KB shared by all branches
  const int tid = threadIdx.x, lane = tid & 63, w = tid >> 6;
  const int r0 = lane & 15, kg = lane >> 4;

  if (!has_scan || blockIdx.x != 0){
    int jb = (int)blockIdx.x - has_scan;
    int ji = 0;
    while (jb >= pa.j[ji].nblocks){ jb -= pa.j[ji].nblocks; ++ji; }
    const Job J = pa.j[ji];

    if (J.type == 1){
      // ---- combine: 4 rows/block, 512 threads, 2 f32/thread ----
      float* red  = (float*)lds;        // [512]
      float* red2 = red + 512;          // [512]
      float* y = (float*)J.Cf;
      const short* e0 = J.A; const short* e1 = J.Bw;
      const float* rw = J.bias; const float* rb = J.add0; const float* fw = J.add1;
      short* y2bf = J.C2;
      int c = J.bm0;
      float2 w0  = *(const float2*)&rw[tid*2];
      float2 w1  = *(const float2*)&rw[1024 + tid*2];
      float2 fw2 = *(const float2*)&fw[tid*2];
      float rb0 = rb[0], rb1 = rb[1];
      for (int rr = 0; rr < 4; ++rr){
        int rl = jb*4 + rr;
        int b = rl >> 8, t = c*256 + (rl & 255);
        size_t base = ((size_t)b*LL + t)*1024 + tid*2;
        float2 vy = *(const float2*)&y[base];
        short2 s0 = *(const short2*)&e0[base];
        short2 s1 = *(const short2*)&e1[base];
        float d0 = vy.x*w0.x + vy.y*w0.y;
        float d1 = vy.x*w1.x + vy.y*w1.y;
        red[tid] = d0; red2[tid] = d1; __syncthreads();
        for (int s = 256; s > 0; s >>= 1){
          if (tid < s){ red[tid] += red[tid+s]; red2[tid] += red2[tid+s]; }
          __syncthreads();
        }
        float l0 = red[0] + rb0, l1 = red2[0] + rb1;
        float p0 = 1.f/(1.f + __expf(l1 - l0));
        float p1 = 1.f - p0;
        float c0 = vy.x + p0*b2f(s0.x) + p1*b2f(s1.x);
        float c1 = vy.y + p0*b2f(s0.y) + p1*b2f(s1.y);
        float ss = c0*c0 + c1*c1;
        __syncthreads();
        red[tid] = ss; __syncthreads();
        for (int s = 256; s > 0; s >>= 1){
          if (tid < s) red[tid] += red[tid+s];
          __syncthreads();
        }
        float scale = rsqrtf(red[0]/1024.f + 1e-6f);
        float o0 = c0*fw2.x*scale, o1 = c1*fw2.y*scale;
        float2 ov; ov.x = o0; ov.y = o1;
        *(float2*)&y[base] = ov;
        short2 ob; ob.x = f2b(o0); ob.y = f2b(o1);
        *(short2*)&y2bf[base] = ob;
        __syncthreads();
      }
      return;
    }

    // ---- generic 128x128 GEMM job ----
    int bnidx = jb % J.bn;
    int lb2 = jb / J.bn;
    int bm;
    if (J.remap == 0) bm = J.bm0 + lb2;
    else { int c = J.cstart + (lb2 >> 3); int q = lb2 & 7; bm = (q>>1)*16 + c*2 + (q&1); }
    short* As = lds;
    short* Bs = lds + 4096;
    int wm = (w >> 2)*64, wn = (w & 3)*32;
    f32x4 acc[4][2];
    #pragma unroll
    for (int i = 0; i < 4; ++i)
      #pragma unroll
      for (int j = 0; j < 2; ++j)
        #pragma unroll
        for (int r = 0; r < 4; ++r) acc[i][j][r] = 0.f;

    const short* ag = J.A  + (size_t)(bm*128    + (tid >> 2))*J.lda + (tid & 3)*8;
    const short* bg = J.Bw + (size_t)(bnidx*128 + (tid >> 2))*J.ldb + (tid & 3)*8;

    for (int k0 = 0; k0 < J.K; k0 += 32){
      __builtin_amdgcn_global_load_lds((const __attribute__((address_space(1))) void*)(ag + k0),
                                       (__attribute__((address_space(3))) void*)&As[w*512], 16, 0, 0);
      __builtin_amdgcn_global_load_lds((const __attribute__((address_space(1))) void*)(bg + k0),
                                       (__attribute__((address_space(3))) void*)&Bs[w*512], 16, 0, 0);
      __syncthreads();
      bf16x8 av[4], bv[2];
      #pragma unroll
      for (int i = 0; i < 4; ++i) av[i] = *(const bf16x8*)&As[(wm + i*16 + r0)*32 + kg*8];
      #pragma unroll
      for (int j = 0; j < 2; ++j) bv[j] = *(const bf16x8*)&Bs[(wn + j*16 + r0)*32 + kg*8];
      #pragma unroll
      for (int i = 0; i < 4; ++i)
        #pragma unroll
        for (int j = 0; j < 2; ++j)
          acc[i][j] = __builtin_amdgcn_mfma_f32_16x16x32_bf16(av[i], bv[j], acc[i][j], 0, 0, 0);
      __syncthreads();
    }
    #pragma unroll
    for (int i = 0; i < 4; ++i){
      #pragma unroll
      for (int j = 0; j < 2; ++j){
        int gc = bnidx*128 + wn + j*16 + r0;
        float bvv = J.bias ? J.bias[gc] : 0.f;
        #pragma unroll
        for (int r = 0; r < 4; ++r){
          int gr = bm*128 + wm + i*16 + kg*4 + r;
          float v = acc[i][j][r] + bvv;
          if (J.act == 1) v = v / (1.f + __expf(-v));
          else if (J.act == 2) v = 0.5f*v*(1.f + erff(v*0.70710678118f));
          size_t orow = J.permute ? (size_t)((gr & 3)*LL + (gr >> 2)) : (size_t)gr;
          size_t oi = orow*(size_t)J.N + gc;
          if (J.add0) v += J.add0[oi];
          if (J.add1) v += J.add1[oi];
          if (J.outmode == 0) ((float*)J.Cf)[oi] = v;
          else if (J.outmode == 2) ((short*)J.Cf)[oi] = f2b(v);
          else {
            float nv = ((float*)J.Cf)[oi] + v;
            ((float*)J.Cf)[oi] = nv;
            J.C2[oi] = f2b(nv);
          }
        }
      }
    }
    return;
  }

  // ---------- scan chunk (block 0) ----------
  short* mA0 = lds;            // [4][272] x2 buffers
  short* mA1 = lds + 1088;
  const int j0 = w*32 + r0;

  bf16x8 bw[2][2][8];
  #pragma unroll
  for (int fu = 0; fu < 2; ++fu)
    #pragma unroll
    for (int p = 0; p < 2; ++p)
      #pragma unroll
      for (int kt = 0; kt < 8; ++kt){
        i32x4 ld = *(const i32x4*)&Wfu[(size_t)(fu*256 + w*32 + p*16 + r0)*256 + kt*32 + kg*8];
        asm volatile("" : "+v"(ld));
        bw[fu][p][kt] = __builtin_bit_cast(bf16x8, ld);
      }

  const float* msrc = (t0 == 0) ? m0 : mstate;
  float m_reg0 = msrc[kg*256 + j0];
  float m_reg1 = msrc[kg*256 + j0 + 16];

  const float* pfu;
  const float* px;
  short* pm = m2all + (size_t)t0*1024 + kg*256 + j0;
  float cf0, cf1, cu0, cu1, xmc0, xmc1, nx0, nx1;
  {
    const float* b0p = fxu + ((size_t)kg*LL + t0)*768 + j0;
    cf0 = b0p[0];    cf1 = b0p[16];
    cu0 = b0p[256];  cu1 = b0p[272];
    float tx0 = b0p[512], tx1 = b0p[528];
    xmc0 = tx0*fsigmoid(tx0);  xmc1 = tx1*fsigmoid(tx1);
    nx0 = b0p[768 + 512];  nx1 = b0p[768 + 528];
    pfu = b0p + 768;
    px  = b0p + 2*768 + 512;
  }
  mA0[kg*272 + j0]      = f2b(m_reg0);
  mA0[kg*272 + j0 + 16] = f2b(m_reg1);
  __syncthreads();

  const short* mac = mA0;
  short*       man = mA1;

#define SCAN_STEP(DO_FU, DO_X)                                                         \
  {                                                                                    \
    bf16x8 af[8];                                                                      \
    _Pragma("unroll")                                                                  \
    for (int kt = 0; kt < 8; ++kt)                                                     \
      af[kt] = *(const bf16x8*)&mac[(r0 & 3)*272 + kt*32 + kg*8];                      \
    float xmn0 = nx0*fsigmoid(nx0);                                                    \
    float xmn1 = nx1*fsigmoid(nx1);                                                    \
    __builtin_amdgcn_s_setprio(1);                                                     \
    f32x4 aF0 = {0.f,0.f,0.f,0.f}, aF1 = {0.f,0.f,0.f,0.f};                            \
    f32x4 aU0 = {0.f,0.f,0.f,0.f}, aU1 = {0.f,0.f,0.f,0.f};                            \
    _Pragma("unroll")                                                                  \
    for (int kt = 0; kt < 8; ++kt){                                                    \
      aF0 = __builtin_amdgcn_mfma_f32_16x16x32_bf16(af[kt], bw[0][0][kt], aF0, 0, 0, 0); \
      aF1 = __builtin_amdgcn_mfma_f32_16x16x32_bf16(af[kt], bw[0][1][kt], aF1, 0, 0, 0); \
      aU0 = __builtin_amdgcn_mfma_f32_16x16x32_bf16(af[kt], bw[1][0][kt], aU0, 0, 0, 0); \
      aU1 = __builtin_amdgcn_mfma_f32_16x16x32_bf16(af[kt], bw[1][1][kt], aU1, 0, 0, 0); \
    }                                                                                  \
    __builtin_amdgcn_s_setprio(0);                                                     \
    float gF0 = sel4(aF0, kg), gF1 = sel4(aF1, kg);                                    \
    float gU0 = sel4(aU0, kg), gU1 = sel4(aU1, kg);                                    \
    float f0 = fsigmoid(gF0 + cf0);                                                    \
    float f1 = fsigmoid(gF1 + cf1);                                                    \
    float u0 = fsigmoid(gU0 + cu0);                                                    \
    float u1 = fsigmoid(gU1 + cu1);                                                    \
    m_reg0 = f0*m_reg0 + u0*xmc0;                                                      \
    m_reg1 = f1*m_reg1 + u1*xmc1;                                                      \
    short mb0 = f2b(m_reg0), mb1 = f2b(m_reg1);                                        \
    pm[0] = mb0; pm[16] = mb1; pm += 1024;                                             \
    xmc0 = xmn0; xmc1 = xmn1;                                                          \
    if (DO_FU){                                                                        \
      cf0 = pfu[0];    cf1 = pfu[16];                                                  \
      cu0 = pfu[256];  cu1 = pfu[272];                                                 \
      pfu += 768;                                                                      \
    }                                                                                  \
    if (DO_X){                                                                         \
      nx0 = px[0]; nx1 = px[16]; px += 768;                                            \
    }                                                                                  \
    man[kg*272 + j0]      = mb0;                                                       \
    man[kg*272 + j0 + 16] = mb1;                                                       \
    asm volatile("s_waitcnt lgkmcnt(0)" ::: "memory");                                 \
    __builtin_amdgcn_sched_barrier(0);                                                 \
    __builtin_amdgcn_s_barrier();                                                      \
    __builtin_amdgcn_sched_barrier(0);                                                 \
    { const short* tmp_ = mac; mac = man; man = (short*)tmp_; }                        \
  }

  for (int t = 0; t < nsteps - 2; ++t) SCAN_STEP(1, 1)
  SCAN_STEP(1, 0)
  SCAN_STEP(0, 0)
#undef SCAN_STEP

  mstate[kg*256 + j0]      = m_reg0;
  mstate[kg*256 + j0 + 16] = m_reg1;
  if (t0 + nsteps == LL){
    newmem[kg*256 + j0]      = m_reg0;
    newmem[kg*256 + j0 + 16] = m_reg1;
  }
}

// ---------------- host ----------------
extern "C" void kernel_launch(void* const* d_in, const int* in_sizes, int n_in,
                              void* d_out, int out_size, void* d_ws, size_t ws_size,
                              hipStream_t stream){
  (void)in_sizes; (void)n_in; (void)out_size; (void)ws_size;
  const float* x     = (const float*)d_in[0];
  const float* mem0  = (const float*)d_in[1];
  const float* normw = (const float*)d_in[2];
  const float* dwk   = (const float*)d_in[3];
  const float* dwb   = (const float*)d_in[4];
  const float* pw    = (const float*)d_in[5];
  const float* pwb   = (const float*)d_in[6];
  const float* Win_w = (const float*)d_in[7];
  const float* Win_b = (const float*)d_in[8];
  const float* Wf_w  = (const float*)d_in[9];
  const float* Wf_b  = (const float*)d_in[10];
  const float* Wu_w  = (const float*)d_in[11];
  const float* Wu_b  = (const float*)d_in[12];
  const float* Wo_w  = (const float*)d_in[13];
  const float* Wo_b  = (const float*)d_in[14];
  const float* rw    = (const float*)d_in[15];
  const float* rb    = (const float*)d_in[16];
  const float* e0w1  = (const float*)d_in[17];
  const float* e0b1  = (const float*)d_in[18];
  const float* e0w2  = (const float*)d_in[19];
  const float* e0b2  = (const float*)d_in[20];
  const float* e1w1  = (const float*)d_in[21];
  const float* e1b1  = (const float*)d_in[22];
  const float* e1w2  = (const float*)d_in[23];
  const float* e1b2  = (const float*)d_in[24];
  const float* fnw   = (const float*)d_in[25];
  const float* dnw   = (const float*)d_in[26];
  const float* dnb   = (const float*)d_in[27];
  const float* upw   = (const float*)d_in[28];
  const float* upb   = (const float*)d_in[29];

  char* ws = (char*)d_ws;
  size_t off = 0;
  auto alloc = [&](size_t bytes)->char*{
    char* p = ws + off; off += (bytes + 255) & ~(size_t)255; return p;
  };
  short* A2       = (short*)alloc((size_t)NROWS*2048*2);
  short* B2       = (short*)alloc((size_t)1024*2048*2);
  short* W_fxuwin = (short*)alloc((size_t)768*1024*2);
  short* W_fum    = (short*)alloc((size_t)512*256*2);
  short* W_om     = (short*)alloc((size_t)1024*256*2);
  short* W_e01    = (short*)alloc((size_t)2048*1024*2);
  short* W_e0w2   = (short*)alloc((size_t)1024*1024*2);
  short* W_e1w2   = (short*)alloc((size_t)1024*1024*2);
  short* W_down   = (short*)alloc((size_t)256*1024*2);
  short* W_up     = (short*)alloc((size_t)1024*256*2);
  float* bias768  = (float*)alloc(768*4);
  float* bias2    = (float*)alloc(1024*4);
  float* bias01   = (float*)alloc(2048*4);
  float* mstate   = (float*)alloc(1024*4);
  float* fxu      = (float*)alloc((size_t)NROWS*768*4);
  float* ybuf     = (float*)alloc((size_t)NROWS*DD*4);
  short* m2all    = (short*)alloc((size_t)NROWS*MDD*2);
  short* ybf      = (short*)alloc((size_t)NROWS*DD*2);
  short* e0v      = (short*)alloc((size_t)NROWS*DD*2);
  short* e1v      = (short*)alloc((size_t)NROWS*DD*2);
  short* h01      = (short*)alloc((size_t)NROWS*2048*2);
  short* hd       = (short*)alloc((size_t)NROWS*MDD*2);   // separate (pipelining!)
  float* newmem   = (float*)d_out + (size_t)NROWS*DD;

  // ---- weight conversion (one launch) ----
  CvtArgs ca;
  auto D0 = [&](const float* s, short* db, int rows, int cols, int sld, int soff, int dld){
    return CvtDesc{s, nullptr, db, nullptr, rows*cols, cols, sld, soff, dld, 0};
  };
  auto D1 = [&](const float* s, float* df, int n){
    return CvtDesc{s, nullptr, nullptr, df, n, n, 0, 0, 0, 1};
  };
  ca.d[0]  = D0(Wo_w,  B2,                1024, 1024, 1280, 0,    2048);
  ca.d[1]  = D0(pw,    B2+1024,           1024, 1024, 1024, 0,    2048);
  ca.d[2]  = D0(Wf_w,  W_fxuwin,           256, 1024, 1280, 0,    1024);
  ca.d[3]  = D0(Wu_w,  W_fxuwin+256*1024,  256, 1024, 1280, 0,    1024);
  ca.d[4]  = D0(Win_w, W_fxuwin+512*1024,  256, 1024, 1024, 0,    1024);
  ca.d[5]  = D0(Wf_w,  W_fum,              256,  256, 1280, 1024, 256);
  ca.d[6]  = D0(Wu_w,  W_fum+256*256,      256,  256, 1280, 1024, 256);
  ca.d[7]  = D0(Wo_w,  W_om,              1024,  256, 1280, 1024, 256);
  ca.d[8]  = D0(e0w1,  W_e01,             1024, 1024, 1024, 0,    1024);
  ca.d[9]  = D0(e1w1,  W_e01+1024*1024,   1024, 1024, 1024, 0,    1024);
  ca.d[10] = D0(e0w2,  W_e0w2,            1024, 1024, 1024, 0,    1024);
  ca.d[11] = D0(e1w2,  W_e1w2,            1024, 1024, 1024, 0,    1024);
  ca.d[12] = D0(dnw,   W_down,             256, 1024, 1024, 0,    1024);
  ca.d[13] = D0(upw,   W_up,              1024,  256,  256, 0,    256);
  ca.d[14] = D1(Wf_b,  bias768,       256);
  ca.d[15] = D1(Wu_b,  bias768+256,   256);
  ca.d[16] = D1(Win_b, bias768+512,   256);
  ca.d[17] = CvtDesc{Wo_b, pwb, nullptr, bias2, 1024, 1024, 0, 0, 0, 2};
  ca.d[18] = D1(e0b1,  bias01,       1024);
  ca.d[19] = D1(e1b1,  bias01+1024,  1024);
  cvt_all<<<20*64, 256, 0, stream>>>(ca);

  rmsnorm_k<<<NROWS, 256, 0, stream>>>(x, normw, A2);
  dwconv_k<<<(NROWS*DD)/256, 256, 0, stream>>>(A2, dwk, dwb, A2);

  // ---- job builders ----
  auto JG = [&](const short* A, const short* Bw, const float* bias,
                const float* a0, const float* a1, void* Cf, short* C2,
                int N, int K, int lda, int ldb, int bn, int nbm, int bm0, int cstart,
                int act, int outm, int perm, int remap)->Job{
    return Job{A, Bw, bias, a0, a1, Cf, C2, N, K, lda, ldb, bn, nbm*bn, bm0, cstart,
               act, outm, perm, remap, 0};
  };
  auto G2j   = [&](int cstart, int nch)->Job{
    return JG(A2, W_fxuwin, bias768, nullptr, nullptr, fxu, nullptr,
              768, 1024, 2048, 1024, 6, nch*8, 0, cstart, 0, 0, 0, 1); };
  Job G34j   = JG(A2, B2, bias2, x, nullptr, ybuf, nullptr,
                  1024, 2048, 2048, 2048, 8, 64, 0, 0, 0, 0, 0, 0);
  auto G5j   = [&](int k)->Job{
    return JG(m2all, W_om, nullptr, nullptr, nullptr, ybuf, ybf,
              1024, 256, 256, 256, 8, 8, k*8, 0, 0, 3, 1, 0); };
  auto E1j   = [&](int k)->Job{
    return JG(ybf, W_e01, bias01, nullptr, nullptr, h01, nullptr,
              2048, 1024, 1024, 1024, 16, 8, 0, k, 1, 2, 0, 1); };
  auto E2aj  = [&](int k)->Job{
    return JG(h01, W_e0w2, e0b2, nullptr, nullptr, e0v, nullptr,
              1024, 1024, 2048, 1024, 8, 8, 0, k, 0, 2, 0, 1); };
  auto E2bj  = [&](int k)->Job{
    return JG(h01+1024, W_e1w2, e1b2, nullptr, nullptr, e1v, nullptr,
              1024, 1024, 2048, 1024, 8, 8, 0, k, 0, 2, 0, 1); };
  auto CBj   = [&](int k)->Job{
    return Job{(const short*)e0v, (const short*)e1v, rw, rb, fnw, ybuf, ybf,
               0, 0, 0, 0, 0, 256, k, 0, 0, 0, 0, 0, 1}; };
  auto G10j  = [&](int k)->Job{
    return JG(ybf, W_down, dnb, nullptr, nullptr, hd, nullptr,
              256, 1024, 1024, 1024, 2, 8, 0, k, 2, 2, 0, 1); };
  auto G11j  = [&](int k)->Job{
    return JG(hd, W_up, upb, ybuf, x, (float*)d_out, nullptr,
              1024, 256, 256, 256, 8, 8, 0, k, 0, 0, 0, 1); };

  auto launch = [&](int t0, int nsteps, std::initializer_list<Job> jobs){
    PipeArgs pa{}; int nb = 0, nj = 0;
    for (const Job& j : jobs){ pa.j[nj++] = j; nb += j.nblocks; }
    pa.njobs = nj;
    int has = nsteps > 0 ? 1 : 0;
    pipe_k<<<has + nb, 512, 0, stream>>>(fxu, W_fum, mem0, mstate, m2all, newmem,
                                         t0, nsteps, has, pa);
  };

  // prologue: G2 chunk 0 only (48 blocks)
  launch(0, 0, { G2j(0, 1) });
  // pipelined scan chunks + downstream stages (stage for chunk k rides dispatch k+offset)
  launch(0*TCH, TCH, { G2j(1, 7), G34j });
  launch(1*TCH, TCH, { G5j(0) });
  launch(2*TCH, TCH, { G5j(1), E1j(0) });
  launch(3*TCH, TCH, { G5j(2), E1j(1), E2aj(0), E2bj(0) });
  launch(4*TCH, TCH, { G5j(3), E1j(2), E2aj(1), E2bj(1), CBj(0) });
  launch(5*TCH, TCH, { G5j(4), E1j(3), E2aj(2), E2bj(2), CBj(1), G10j(0) });
  launch(6*TCH, TCH, { G5j(5), E1j(4), E2aj(3), E2bj(3), CBj(2), G10j(1), G11j(0) });
  launch(7*TCH, TCH, { G5j(6), E1j(5), E2aj(4), E2bj(4), CBj(3), G10j(2), G11j(1) });
  // drain
  launch(0, 0, { G5j(7), E1j(6), E2aj(5), E2bj(5), CBj(4), G10j(3), G11j(2) });
  launch(0, 0, { E1j(7), E2aj(6), E2bj(6), CBj(5), G10j(4), G11j(3) });
  launch(0, 0, { E2aj(7), E2bj(7), CBj(6), G10j(5), G11j(4) });
  launch(0, 0, { CBj(7), G10j(6), G11j(5) });
  launch(0, 0, { G10j(7), G11j(6) });
  launch(0, 0, { G11j(7) });
}

// Round 10
// 1982.320 us; speedup vs baseline: 1.0104x; 1.0104x over previous
//
#include <hip/hip_runtime.h>
#include <hip/hip_bf16.h>
#include <initializer_list>

#define DD 1024
#define MDD 256
#define LL 2048
#define BB 4
#define NROWS (BB*LL)   // 8192
#define NCH 8
#define TCH (LL/NCH)    // 256 steps per chunk

typedef short bf16x8 __attribute__((ext_vector_type(8)));
typedef float f32x4 __attribute__((ext_vector_type(4)));
typedef int   i32x4 __attribute__((ext_vector_type(4)));

__device__ __forceinline__ short f2b(float x){
  __hip_bfloat16 h = __float2bfloat16(x);
  return *reinterpret_cast<short*>(&h);
}
__device__ __forceinline__ float b2f(short s){
  return __uint_as_float(((unsigned)(unsigned short)s) << 16);
}
__device__ __forceinline__ float frcp(float x){
#if __has_builtin(__builtin_amdgcn_rcpf)
  return __builtin_amdgcn_rcpf(x);
#else
  float r; asm("v_rcp_f32 %0, %1" : "=v"(r) : "v"(x)); return r;
#endif
}
__device__ __forceinline__ float fsigmoid(float x){
  return frcp(1.f + __expf(-x));
}
__device__ __forceinline__ float sel4(f32x4 a, int kg){
  float lo = (kg & 1) ? a[1] : a[0];
  float hi = (kg & 1) ? a[3] : a[2];
  return (kg & 2) ? hi : lo;
}

// ---------------- fused weight conversion / bias prep ----------------
struct CvtDesc {
  const float* src; const float* src2; short* dstb; float* dstf;
  int n, cols, sld, soff, dld, mode;
};
struct CvtArgs { CvtDesc d[20]; };

__global__ __launch_bounds__(256) void cvt_all(CvtArgs a){
  int di = blockIdx.x >> 6;
  CvtDesc d = a.d[di];
  int base = (blockIdx.x & 63)*256 + threadIdx.x;
  for (int i = base; i < d.n; i += 64*256){
    int r = i / d.cols, c = i - r*d.cols;
    float v = d.src[(size_t)r*d.sld + d.soff + c];
    if (d.mode == 2) v += d.src2[i];
    if (d.mode == 0) d.dstb[(size_t)r*d.dld + c] = f2b(v);
    else             d.dstf[i] = v;
  }
}

// ---------------- rmsnorm (f32 in -> bf16 out, strided out) ----------------
__global__ __launch_bounds__(256) void rmsnorm_k(const float* __restrict__ x,
                                                 const float* __restrict__ w,
                                                 short* __restrict__ xn){
  int row = blockIdx.x, tid = threadIdx.x;
  const float* xr = x + (size_t)row*DD;
  float4 v = *(const float4*)&xr[tid*4];
  float ss = v.x*v.x + v.y*v.y + v.z*v.z + v.w*v.w;
  __shared__ float red[256];
  red[tid] = ss; __syncthreads();
  for (int s = 128; s > 0; s >>= 1){ if (tid < s) red[tid] += red[tid+s]; __syncthreads(); }
  float scale = rsqrtf(red[0]/(float)DD + 1e-6f);
  const float* wr = w + tid*4;
  short4 o;
  o.x = f2b(v.x*wr[0]*scale); o.y = f2b(v.y*wr[1]*scale);
  o.z = f2b(v.z*wr[2]*scale); o.w = f2b(v.w*wr[3]*scale);
  *(short4*)&xn[(size_t)row*2048 + tid*4] = o;
}

// ---------------- depthwise causal conv K=5 ----------------
__global__ __launch_bounds__(256) void dwconv_k(const short* __restrict__ xnA,
                                                const float* __restrict__ dwk,
                                                const float* __restrict__ dwb,
                                                short* __restrict__ xcA){
  size_t i = (size_t)blockIdx.x*256 + threadIdx.x;
  int d = (int)(i & (DD-1));
  int l = (int)((i >> 10) & (LL-1));
  int b = (int)(i >> 21);
  float acc = dwb[d];
  const float* kk = dwk + d*5;
  #pragma unroll
  for (int k = 0; k < 5; ++k){
    int ll = l + k - 4;
    if (ll >= 0) acc += b2f(xnA[((size_t)(b*LL + ll))*2048 + d]) * kk[k];
  }
  xcA[((size_t)(b*LL + l))*2048 + 1024 + d] = f2b(acc);
}

// ---------------- pipelined fused dispatch ----------------
// Job types: 0 = 128x128 GEMM (8 waves, wave = 64x32 subtile), 1 = combine.
// remap 0: bm = bm0 + lb2. remap 1 (row-space b*L+t chunk interleave):
//   c = cstart + (lb2>>3), q = lb2&7, bm = (q>>1)*16 + c*2 + (q&1).
struct Job {
  const short* A; const short* Bw; const float* bias;
  const float* add0; const float* add1; void* Cf; short* C2;
  int N, K, lda, ldb, bn, nblocks, bm0, cstart, act, outmode, permute, remap, type;
};
struct PipeArgs { Job j[12]; int njobs; };

// PAD=1: 40 laundered VGPRs force VGPR_Count > 128 -> one 512-thread block per CU
// -> the scan block owns its CU exclusively (no MFMA-pipe contention on the serial path).
template<int PAD>
__global__ __launch_bounds__(512, 2) void pipe_k(
    const float* __restrict__ fxu, const short* __restrict__ Wfu,
    const float* __restrict__ m0, float* __restrict__ mstate,
    short* __restrict__ m2all, float* __restrict__ newmem,
    int t0, int nsteps, int has_scan, PipeArgs pa){
  __shared__ __align__(16) short lds[8192];
  const int tid = threadIdx.x, lane = tid & 63, w = tid >> 6;
  const int r0 = lane & 15, kg = lane >> 4;

  i32x4 p0, p1, p2, p3, p4, p5, p6, p7, p8, p9;
  if (PAD){
    p0 = i32x4{0,0,0,0}; asm volatile("" : "+v"(p0));
    p1 = i32x4{0,0,0,0}; asm volatile("" : "+v"(p1));
    p2 = i32x4{0,0,0,0}; asm volatile("" : "+v"(p2));
    p3 = i32x4{0,0,0,0}; asm volatile("" : "+v"(p3));
    p4 = i32x4{0,0,0,0}; asm volatile("" : "+v"(p4));
    p5 = i32x4{0,0,0,0}; asm volatile("" : "+v"(p5));
    p6 = i32x4{0,0,0,0}; asm volatile("" : "+v"(p6));
    p7 = i32x4{0,0,0,0}; asm volatile("" : "+v"(p7));
    p8 = i32x4{0,0,0,0}; asm volatile("" : "+v"(p8));
    p9 = i32x4{0,0,0,0}; asm volatile("" : "+v"(p9));
  }
#define PAD_SINK() if (PAD) asm volatile("" :: "v"(p0),"v"(p1),"v"(p2),"v"(p3),"v"(p4),"v"(p5),"v"(p6),"v"(p7),"v"(p8),"v"(p9))

  if (!has_scan || blockIdx.x != 0){
    int jb = (int)blockIdx.x - has_scan;
    int ji = 0;
    while (jb >= pa.j[ji].nblocks){ jb -= pa.j[ji].nblocks; ++ji; }
    const Job J = pa.j[ji];

    if (J.type == 1){
      // ---- combine: 4 rows/block, 512 threads, 2 f32/thread ----
      float* red  = (float*)lds;
      float* red2 = red + 512;
      float* y = (float*)J.Cf;
      const short* e0 = J.A; const short* e1 = J.Bw;
      const float* rw = J.bias; const float* rb = J.add0; const float* fw = J.add1;
      short* y2bf = J.C2;
      int c = J.bm0;
      float2 w0  = *(const float2*)&rw[tid*2];
      float2 w1  = *(const float2*)&rw[1024 + tid*2];
      float2 fw2 = *(const float2*)&fw[tid*2];
      float rb0 = rb[0], rb1 = rb[1];
      for (int rr = 0; rr < 4; ++rr){
        int rl = jb*4 + rr;
        int b = rl >> 8, t = c*256 + (rl & 255);
        size_t base = ((size_t)b*LL + t)*1024 + tid*2;
        float2 vy = *(const float2*)&y[base];
        short2 s0 = *(const short2*)&e0[base];
        short2 s1 = *(const short2*)&e1[base];
        float d0 = vy.x*w0.x + vy.y*w0.y;
        float d1 = vy.x*w1.x + vy.y*w1.y;
        red[tid] = d0; red2[tid] = d1; __syncthreads();
        for (int s = 256; s > 0; s >>= 1){
          if (tid < s){ red[tid] += red[tid+s]; red2[tid] += red2[tid+s]; }
          __syncthreads();
        }
        float l0 = red[0] + rb0, l1 = red2[0] + rb1;
        float pp0 = 1.f/(1.f + __expf(l1 - l0));
        float pp1 = 1.f - pp0;
        float c0 = vy.x + pp0*b2f(s0.x) + pp1*b2f(s1.x);
        float c1 = vy.y + pp0*b2f(s0.y) + pp1*b2f(s1.y);
        float ss = c0*c0 + c1*c1;
        __syncthreads();
        red[tid] = ss; __syncthreads();
        for (int s = 256; s > 0; s >>= 1){
          if (tid < s) red[tid] += red[tid+s];
          __syncthreads();
        }
        float scale = rsqrtf(red[0]/1024.f + 1e-6f);
        float o0 = c0*fw2.x*scale, o1 = c1*fw2.y*scale;
        float2 ov; ov.x = o0; ov.y = o1;
        *(float2*)&y[base] = ov;
        short2 ob; ob.x = f2b(o0); ob.y = f2b(o1);
        *(short2*)&y2bf[base] = ob;
        __syncthreads();
      }
      PAD_SINK();
      return;
    }

    // ---- generic 128x128 GEMM job ----
    int bnidx = jb % J.bn;
    int lb2 = jb / J.bn;
    int bm;
    if (J.remap == 0) bm = J.bm0 + lb2;
    else { int c = J.cstart + (lb2 >> 3); int q = lb2 & 7; bm = (q>>1)*16 + c*2 + (q&1); }
    short* As = lds;
    short* Bs = lds + 4096;
    int wm = (w >> 2)*64, wn = (w & 3)*32;
    f32x4 acc[4][2];
    #pragma unroll
    for (int i = 0; i < 4; ++i)
      #pragma unroll
      for (int j = 0; j < 2; ++j)
        #pragma unroll
        for (int r = 0; r < 4; ++r) acc[i][j][r] = 0.f;

    const short* ag = J.A  + (size_t)(bm*128    + (tid >> 2))*J.lda + (tid & 3)*8;
    const short* bg = J.Bw + (size_t)(bnidx*128 + (tid >> 2))*J.ldb + (tid & 3)*8;

    for (int k0 = 0; k0 < J.K; k0 += 32){
      __builtin_amdgcn_global_load_lds((const __attribute__((address_space(1))) void*)(ag + k0),
                                       (__attribute__((address_space(3))) void*)&As[w*512], 16, 0, 0);
      __builtin_amdgcn_global_load_lds((const __attribute__((address_space(1))) void*)(bg + k0),
                                       (__attribute__((address_space(3))) void*)&Bs[w*512], 16, 0, 0);
      __syncthreads();
      bf16x8 av[4], bv[2];
      #pragma unroll
      for (int i = 0; i < 4; ++i) av[i] = *(const bf16x8*)&As[(wm + i*16 + r0)*32 + kg*8];
      #pragma unroll
      for (int j = 0; j < 2; ++j) bv[j] = *(const bf16x8*)&Bs[(wn + j*16 + r0)*32 + kg*8];
      #pragma unroll
      for (int i = 0; i < 4; ++i)
        #pragma unroll
        for (int j = 0; j < 2; ++j)
          acc[i][j] = __builtin_amdgcn_mfma_f32_16x16x32_bf16(av[i], bv[j], acc[i][j], 0, 0, 0);
      __syncthreads();
    }
    #pragma unroll
    for (int i = 0; i < 4; ++i){
      #pragma unroll
      for (int j = 0; j < 2; ++j){
        int gc = bnidx*128 + wn + j*16 + r0;
        float bvv = J.bias ? J.bias[gc] : 0.f;
        #pragma unroll
        for (int r = 0; r < 4; ++r){
          int gr = bm*128 + wm + i*16 + kg*4 + r;
          float v = acc[i][j][r] + bvv;
          if (J.act == 1) v = v / (1.f + __expf(-v));
          else if (J.act == 2) v = 0.5f*v*(1.f + erff(v*0.70710678118f));
          size_t orow = J.permute ? (size_t)((gr & 3)*LL + (gr >> 2)) : (size_t)gr;
          size_t oi = orow*(size_t)J.N + gc;
          if (J.add0) v += J.add0[oi];
          if (J.add1) v += J.add1[oi];
          if (J.outmode == 0) ((float*)J.Cf)[oi] = v;
          else if (J.outmode == 2) ((short*)J.Cf)[oi] = f2b(v);
          else {
            float nv = ((float*)J.Cf)[oi] + v;
            ((float*)J.Cf)[oi] = nv;
            J.C2[oi] = f2b(nv);
          }
        }
      }
    }
    PAD_SINK();
    return;
  }

  // ---------- scan chunk (block 0) ----------
  short* mA0 = lds;
  short* mA1 = lds + 1088;
  const int j0 = w*32 + r0;

  bf16x8 bw[2][2][8];
  #pragma unroll
  for (int fu = 0; fu < 2; ++fu)
    #pragma unroll
    for (int p = 0; p < 2; ++p)
      #pragma unroll
      for (int kt = 0; kt < 8; ++kt){
        i32x4 ld = *(const i32x4*)&Wfu[(size_t)(fu*256 + w*32 + p*16 + r0)*256 + kt*32 + kg*8];
        asm volatile("" : "+v"(ld));
        bw[fu][p][kt] = __builtin_bit_cast(bf16x8, ld);
      }

  const float* msrc = (t0 == 0) ? m0 : mstate;
  float m_reg0 = msrc[kg*256 + j0];
  float m_reg1 = msrc[kg*256 + j0 + 16];

  const float* pfu;
  const float* px;
  short* pm = m2all + (size_t)t0*1024 + kg*256 + j0;
  float cf0, cf1, cu0, cu1, xmc0, xmc1, nx0, nx1;
  {
    const float* b0p = fxu + ((size_t)kg*LL + t0)*768 + j0;
    cf0 = b0p[0];    cf1 = b0p[16];
    cu0 = b0p[256];  cu1 = b0p[272];
    float tx0 = b0p[512], tx1 = b0p[528];
    xmc0 = tx0*fsigmoid(tx0);  xmc1 = tx1*fsigmoid(tx1);
    nx0 = b0p[768 + 512];  nx1 = b0p[768 + 528];
    pfu = b0p + 768;
    px  = b0p + 2*768 + 512;
  }
  mA0[kg*272 + j0]      = f2b(m_reg0);
  mA0[kg*272 + j0 + 16] = f2b(m_reg1);
  __syncthreads();

  const short* mac = mA0;
  short*       man = mA1;

#define SCAN_STEP(DO_FU, DO_X)                                                         \
  {                                                                                    \
    bf16x8 af[8];                                                                      \
    _Pragma("unroll")                                                                  \
    for (int kt = 0; kt < 8; ++kt)                                                     \
      af[kt] = *(const bf16x8*)&mac[(r0 & 3)*272 + kt*32 + kg*8];                      \
    float xmn0 = nx0*fsigmoid(nx0);                                                    \
    float xmn1 = nx1*fsigmoid(nx1);                                                    \
    __builtin_amdgcn_s_setprio(1);                                                     \
    f32x4 aF0 = {0.f,0.f,0.f,0.f}, aF1 = {0.f,0.f,0.f,0.f};                            \
    f32x4 aU0 = {0.f,0.f,0.f,0.f}, aU1 = {0.f,0.f,0.f,0.f};                            \
    _Pragma("unroll")                                                                  \
    for (int kt = 0; kt < 8; ++kt){                                                    \
      aF0 = __builtin_amdgcn_mfma_f32_16x16x32_bf16(af[kt], bw[0][0][kt], aF0, 0, 0, 0); \
      aF1 = __builtin_amdgcn_mfma_f32_16x16x32_bf16(af[kt], bw[0][1][kt], aF1, 0, 0, 0); \
      aU0 = __builtin_amdgcn_mfma_f32_16x16x32_bf16(af[kt], bw[1][0][kt], aU0, 0, 0, 0); \
      aU1 = __builtin_amdgcn_mfma_f32_16x16x32_bf16(af[kt], bw[1][1][kt], aU1, 0, 0, 0); \
    }                                                                                  \
    __builtin_amdgcn_s_setprio(0);                                                     \
    float gF0 = sel4(aF0, kg), gF1 = sel4(aF1, kg);                                    \
    float gU0 = sel4(aU0, kg), gU1 = sel4(aU1, kg);                                    \
    float f0 = fsigmoid(gF0 + cf0);                                                    \
    float f1 = fsigmoid(gF1 + cf1);                                                    \
    float u0 = fsigmoid(gU0 + cu0);                                                    \
    float u1 = fsigmoid(gU1 + cu1);                                                    \
    m_reg0 = f0*m_reg0 + u0*xmc0;                                                      \
    m_reg1 = f1*m_reg1 + u1*xmc1;                                                      \
    short mb0 = f2b(m_reg0), mb1 = f2b(m_reg1);                                        \
    pm[0] = mb0; pm[16] = mb1; pm += 1024;                                             \
    xmc0 = xmn0; xmc1 = xmn1;                                                          \
    if (DO_FU){                                                                        \
      cf0 = pfu[0];    cf1 = pfu[16];                                                  \
      cu0 = pfu[256];  cu1 = pfu[272];                                                 \
      pfu += 768;                                                                      \
    }                                                                                  \
    if (DO_X){                                                                         \
      nx0 = px[0]; nx1 = px[16]; px += 768;                                            \
    }                                                                                  \
    man[kg*272 + j0]      = mb0;                                                       \
    man[kg*272 + j0 + 16] = mb1;                                                       \
    asm volatile("s_waitcnt lgkmcnt(0)" ::: "memory");                                 \
    __builtin_amdgcn_sched_barrier(0);                                                 \
    __builtin_amdgcn_s_barrier();                                                      \
    __builtin_amdgcn_sched_barrier(0);                                                 \
    { const short* tmp_ = mac; mac = man; man = (short*)tmp_; }                        \
  }

  for (int t = 0; t < nsteps - 2; ++t) SCAN_STEP(1, 1)
  SCAN_STEP(1, 0)
  SCAN_STEP(0, 0)
#undef SCAN_STEP

  mstate[kg*256 + j0]      = m_reg0;
  mstate[kg*256 + j0 + 16] = m_reg1;
  if (t0 + nsteps == LL){
    newmem[kg*256 + j0]      = m_reg0;
    newmem[kg*256 + j0 + 16] = m_reg1;
  }
  PAD_SINK();
#undef PAD_SINK
}

// ---------------- host ----------------
extern "C" void kernel_launch(void* const* d_in, const int* in_sizes, int n_in,
                              void* d_out, int out_size, void* d_ws, size_t ws_size,
                              hipStream_t stream){
  (void)in_sizes; (void)n_in; (void)out_size; (void)ws_size;
  const float* x     = (const float*)d_in[0];
  const float* mem0  = (const float*)d_in[1];
  const float* normw = (const float*)d_in[2];
  const float* dwk   = (const float*)d_in[3];
  const float* dwb   = (const float*)d_in[4];
  const float* pw    = (const float*)d_in[5];
  const float* pwb   = (const float*)d_in[6];
  const float* Win_w = (const float*)d_in[7];
  const float* Win_b = (const float*)d_in[8];
  const float* Wf_w  = (const float*)d_in[9];
  const float* Wf_b  = (const float*)d_in[10];
  const float* Wu_w  = (const float*)d_in[11];
  const float* Wu_b  = (const float*)d_in[12];
  const float* Wo_w  = (const float*)d_in[13];
  const float* Wo_b  = (const float*)d_in[14];
  const float* rw    = (const float*)d_in[15];
  const float* rb    = (const float*)d_in[16];
  const float* e0w1  = (const float*)d_in[17];
  const float* e0b1  = (const float*)d_in[18];
  const float* e0w2  = (const float*)d_in[19];
  const float* e0b2  = (const float*)d_in[20];
  const float* e1w1  = (const float*)d_in[21];
  const float* e1b1  = (const float*)d_in[22];
  const float* e1w2  = (const float*)d_in[23];
  const float* e1b2  = (const float*)d_in[24];
  const float* fnw   = (const float*)d_in[25];
  const float* dnw   = (const float*)d_in[26];
  const float* dnb   = (const float*)d_in[27];
  const float* upw   = (const float*)d_in[28];
  const float* upb   = (const float*)d_in[29];

  char* ws = (char*)d_ws;
  size_t off = 0;
  auto alloc = [&](size_t bytes)->char*{
    char* p = ws + off; off += (bytes + 255) & ~(size_t)255; return p;
  };
  short* A2       = (short*)alloc((size_t)NROWS*2048*2);
  short* B2       = (short*)alloc((size_t)1024*2048*2);
  short* W_fxuwin = (short*)alloc((size_t)768*1024*2);
  short* W_fum    = (short*)alloc((size_t)512*256*2);
  short* W_om     = (short*)alloc((size_t)1024*256*2);
  short* W_e01    = (short*)alloc((size_t)2048*1024*2);
  short* W_e0w2   = (short*)alloc((size_t)1024*1024*2);
  short* W_e1w2   = (short*)alloc((size_t)1024*1024*2);
  short* W_down   = (short*)alloc((size_t)256*1024*2);
  short* W_up     = (short*)alloc((size_t)1024*256*2);
  float* bias768  = (float*)alloc(768*4);
  float* bias2    = (float*)alloc(1024*4);
  float* bias01   = (float*)alloc(2048*4);
  float* mstate   = (float*)alloc(1024*4);
  float* fxu      = (float*)alloc((size_t)NROWS*768*4);
  float* ybuf     = (float*)alloc((size_t)NROWS*DD*4);
  short* m2all    = (short*)alloc((size_t)NROWS*MDD*2);
  short* ybf      = (short*)alloc((size_t)NROWS*DD*2);
  short* e0v      = (short*)alloc((size_t)NROWS*DD*2);
  short* e1v      = (short*)alloc((size_t)NROWS*DD*2);
  short* h01      = (short*)alloc((size_t)NROWS*2048*2);
  short* hd       = (short*)alloc((size_t)NROWS*MDD*2);
  float* newmem   = (float*)d_out + (size_t)NROWS*DD;

  // ---- weight conversion (one launch) ----
  CvtArgs ca;
  auto D0 = [&](const float* s, short* db, int rows, int cols, int sld, int soff, int dld){
    return CvtDesc{s, nullptr, db, nullptr, rows*cols, cols, sld, soff, dld, 0};
  };
  auto D1 = [&](const float* s, float* df, int n){
    return CvtDesc{s, nullptr, nullptr, df, n, n, 0, 0, 0, 1};
  };
  ca.d[0]  = D0(Wo_w,  B2,                1024, 1024, 1280, 0,    2048);
  ca.d[1]  = D0(pw,    B2+1024,           1024, 1024, 1024, 0,    2048);
  ca.d[2]  = D0(Wf_w,  W_fxuwin,           256, 1024, 1280, 0,    1024);
  ca.d[3]  = D0(Wu_w,  W_fxuwin+256*1024,  256, 1024, 1280, 0,    1024);
  ca.d[4]  = D0(Win_w, W_fxuwin+512*1024,  256, 1024, 1024, 0,    1024);
  ca.d[5]  = D0(Wf_w,  W_fum,              256,  256, 1280, 1024, 256);
  ca.d[6]  = D0(Wu_w,  W_fum+256*256,      256,  256, 1280, 1024, 256);
  ca.d[7]  = D0(Wo_w,  W_om,              1024,  256, 1280, 1024, 256);
  ca.d[8]  = D0(e0w1,  W_e01,             1024, 1024, 1024, 0,    1024);
  ca.d[9]  = D0(e1w1,  W_e01+1024*1024,   1024, 1024, 1024, 0,    1024);
  ca.d[10] = D0(e0w2,  W_e0w2,            1024, 1024, 1024, 0,    1024);
  ca.d[11] = D0(e1w2,  W_e1w2,            1024, 1024, 1024, 0,    1024);
  ca.d[12] = D0(dnw,   W_down,             256, 1024, 1024, 0,    1024);
  ca.d[13] = D0(upw,   W_up,              1024,  256,  256, 0,    256);
  ca.d[14] = D1(Wf_b,  bias768,       256);
  ca.d[15] = D1(Wu_b,  bias768+256,   256);
  ca.d[16] = D1(Win_b, bias768+512,   256);
  ca.d[17] = CvtDesc{Wo_b, pwb, nullptr, bias2, 1024, 1024, 0, 0, 0, 2};
  ca.d[18] = D1(e0b1,  bias01,       1024);
  ca.d[19] = D1(e1b1,  bias01+1024,  1024);
  cvt_all<<<20*64, 256, 0, stream>>>(ca);

  rmsnorm_k<<<NROWS, 256, 0, stream>>>(x, normw, A2);
  dwconv_k<<<(NROWS*DD)/256, 256, 0, stream>>>(A2, dwk, dwb, A2);

  // ---- job builders ----
  auto JG = [&](const short* A, const short* Bw, const float* bias,
                const float* a0, const float* a1, void* Cf, short* C2,
                int N, int K, int lda, int ldb, int bn, int nbm, int bm0, int cstart,
                int act, int outm, int perm, int remap)->Job{
    return Job{A, Bw, bias, a0, a1, Cf, C2, N, K, lda, ldb, bn, nbm*bn, bm0, cstart,
               act, outm, perm, remap, 0};
  };
  auto G2j   = [&](int cstart)->Job{
    return JG(A2, W_fxuwin, bias768, nullptr, nullptr, fxu, nullptr,
              768, 1024, 2048, 1024, 6, 8, 0, cstart, 0, 0, 0, 1); };
  auto G34j  = [&](int k)->Job{
    return JG(A2, B2, bias2, x, nullptr, ybuf, nullptr,
              1024, 2048, 2048, 2048, 8, 8, 0, k, 0, 0, 0, 1); };
  auto G5j   = [&](int k)->Job{
    return JG(m2all, W_om, nullptr, nullptr, nullptr, ybuf, ybf,
              1024, 256, 256, 256, 8, 8, k*8, 0, 0, 3, 1, 0); };
  auto E1j   = [&](int k)->Job{
    return JG(ybf, W_e01, bias01, nullptr, nullptr, h01, nullptr,
              2048, 1024, 1024, 1024, 16, 8, 0, k, 1, 2, 0, 1); };
  auto E2aj  = [&](int k)->Job{
    return JG(h01, W_e0w2, e0b2, nullptr, nullptr, e0v, nullptr,
              1024, 1024, 2048, 1024, 8, 8, 0, k, 0, 2, 0, 1); };
  auto E2bj  = [&](int k)->Job{
    return JG(h01+1024, W_e1w2, e1b2, nullptr, nullptr, e1v, nullptr,
              1024, 1024, 2048, 1024, 8, 8, 0, k, 0, 2, 0, 1); };
  auto CBj   = [&](int k)->Job{
    return Job{(const short*)e0v, (const short*)e1v, rw, rb, fnw, ybuf, ybf,
               0, 0, 0, 0, 0, 256, k, 0, 0, 0, 0, 0, 1}; };
  auto G10j  = [&](int k)->Job{
    return JG(ybf, W_down, dnb, nullptr, nullptr, hd, nullptr,
              256, 1024, 1024, 1024, 2, 8, 0, k, 2, 2, 0, 1); };
  auto G11j  = [&](int k)->Job{
    return JG(hd, W_up, upb, ybuf, x, (float*)d_out, nullptr,
              1024, 256, 256, 256, 8, 8, 0, k, 0, 0, 0, 1); };

  auto launch = [&](int t0, int nsteps, std::initializer_list<Job> jobs){
    PipeArgs pa{}; int nb = 0, nj = 0;
    for (const Job& j : jobs){ pa.j[nj++] = j; nb += j.nblocks; }
    pa.njobs = nj;
    int has = nsteps > 0 ? 1 : 0;
    if (has)
      pipe_k<1><<<has + nb, 512, 0, stream>>>(fxu, W_fum, mem0, mstate, m2all, newmem,
                                              t0, nsteps, has, pa);
    else
      pipe_k<0><<<nb, 512, 0, stream>>>(fxu, W_fum, mem0, mstate, m2all, newmem,
                                        t0, nsteps, 0, pa);
  };

  // prologue: G2 chunk 0 (must precede scan chunk 0)
  launch(0, 0, { G2j(0) });
  // scan chunks with staged consumers/producers riding along
  launch(0*TCH, TCH, { G2j(1), G34j(0) });
  launch(1*TCH, TCH, { G2j(2), G34j(1), G5j(0) });
  launch(2*TCH, TCH, { G2j(3), G34j(2), G5j(1), E1j(0) });
  launch(3*TCH, TCH, { G2j(4), G34j(3), G5j(2), E1j(1), E2aj(0), E2bj(0) });
  launch(4*TCH, TCH, { G2j(5), G34j(4), G5j(3), E1j(2), E2aj(1), E2bj(1), CBj(0) });
  launch(5*TCH, TCH, { G2j(6), G34j(5), G5j(4), E1j(3), E2aj(2), E2bj(2), CBj(1), G10j(0) });
  launch(6*TCH, TCH, { G2j(7), G34j(6), G5j(5), E1j(4), E2aj(3), E2bj(3), CBj(2), G10j(1), G11j(0) });
  launch(7*TCH, TCH, { G34j(7), G5j(6), E1j(5), E2aj(4), E2bj(4), CBj(3), G10j(2), G11j(1) });
  // drain (unpadded kernel, 2 blocks/CU)
  launch(0, 0, { G5j(7), E1j(6), E2aj(5), E2bj(5), CBj(4), G10j(3), G11j(2) });
  launch(0, 0, { E1j(7), E2aj(6), E2bj(6), CBj(5), G10j(4), G11j(3) });
  launch(0, 0, { E2aj(7), E2bj(7), CBj(6), G10j(5), G11j(4) });
  launch(0, 0, { CBj(7), G10j(6), G11j(5) });
  launch(0, 0, { G10j(7), G11j(6) });
  launch(0, 0, { G11j(7) });
}